// Round 21
// baseline (118.842 us; speedup 1.0000x reference)
//
#include <hip/hip_runtime.h>
#include <stdint.h>

typedef unsigned short u16;
typedef __attribute__((ext_vector_type(8))) short short8;
typedef __attribute__((ext_vector_type(4))) float f32x4;
typedef __attribute__((ext_vector_type(16))) float f32x16;

__device__ __forceinline__ u16 f2bf(float f) {
  union { float f; unsigned int u; } c; c.f = f;
  return (u16)((c.u + 0x7FFFu + ((c.u >> 16) & 1u)) >> 16);
}

__device__ __forceinline__ float bf2f(u16 v) {
  union { unsigned int u; float f; } c; c.u = ((unsigned int)v) << 16;
  return c.f;
}

__device__ __forceinline__ f32x4 mfma16(short8 a, short8 b, f32x4 c) {
  return __builtin_amdgcn_mfma_f32_16x16x32_bf16(a, b, c, 0, 0, 0);
}

__device__ __forceinline__ f32x16 mfma32(short8 a, short8 b, f32x16 c) {
  return __builtin_amdgcn_mfma_f32_32x32x16_bf16(a, b, c, 0, 0, 0);
}

__device__ __forceinline__ void gl_lds16(const u16* g, u16* l) {
  __builtin_amdgcn_global_load_lds((const __attribute__((address_space(1))) void*)g,
                                   (__attribute__((address_space(3))) void*)l, 16, 0, 0);
}

// ---------------- fused cast f32 -> bf16 ----------------
__global__ __launch_bounds__(256) void cast_all(
    const float* __restrict__ x, const float* __restrict__ wq, const float* __restrict__ wk,
    const float* __restrict__ wv, const float* __restrict__ wo,
    u16* __restrict__ xb, u16* __restrict__ wqb, u16* __restrict__ wkb,
    u16* __restrict__ wvb, u16* __restrict__ wob) {
  int b = blockIdx.x;
  const float* src; u16* dst; int i;
  if (b < 4096)      { src = x;  dst = xb;  i = b * 256 + threadIdx.x; }
  else if (b < 5120) { src = wq; dst = wqb; i = (b - 4096) * 256 + threadIdx.x; }
  else if (b < 6144) { src = wk; dst = wkb; i = (b - 5120) * 256 + threadIdx.x; }
  else if (b < 7168) { src = wv; dst = wvb; i = (b - 6144) * 256 + threadIdx.x; }
  else               { src = wo; dst = wob; i = (b - 7168) * 256 + threadIdx.x; }
  float4 v = ((const float4*)src)[i];
  ushort4 o;
  o.x = f2bf(v.x); o.y = f2bf(v.y); o.z = f2bf(v.z); o.w = f2bf(v.w);
  ((ushort4*)dst)[i] = o;
}

// ---------------- fused QKV projection GEMM (wave-private, barrier-free) ----
// The R15 attn staging schedule transplanted to GEMM: each wave owns private
// double-buffered A(64x32)+B(64x32) LDS panels (16 KB/wave). Pipeline per
// wave: stage(t+1) -> vmcnt(8) -> swizzled ds_read + 16 MFMA -> lgkmcnt(0)
// (drain before re-staging the buffer read last iter). ZERO barriers: the
// per-iteration vmcnt(0)+s_barrier drain that capped all barrier-synced
// variants at ~600 TF is gone. Staging: linear LDS dest + 4-chunk XOR
// pre-swizzled global source + swizzled read (rule #21, attn-proven).
__global__ __launch_bounds__(256) void qkv_gemm(
    const u16* __restrict__ xb, const u16* __restrict__ wqb, const u16* __restrict__ wkb,
    const u16* __restrict__ wvb, const float* __restrict__ bq, const float* __restrict__ bk,
    const float* __restrict__ bv, u16* __restrict__ Qb, u16* __restrict__ Kb,
    u16* __restrict__ VTb) {
  __shared__ __align__(16) char smem[65536];  // 4 waves x (A0|A1|B0|B1) x 4 KB
  const int id = blockIdx.x;
  const int z = id >> 8;
  const int u = id & 255;
  const int mblk = (u & 7) + (((u >> 3) & 3) << 3);
  const int nblk = u >> 5;
  const u16* __restrict__ W = (z == 0) ? wqb : (z == 1) ? wkb : wvb;
  const float* __restrict__ bias = (z == 0) ? bq : (z == 1) ? bk : bv;
  const int m0 = mblk * 128, n0 = nblk * 128;
  const int tid = threadIdx.x, lane = tid & 63, wave = tid >> 6;
  const int wr = (wave >> 1) * 64, wc = (wave & 1) * 64;
  const int fr = lane & 15, fg = lane >> 4;
  const int r16 = lane >> 2;
  const int cswz = (lane & 3) ^ (r16 & 3);  // pre-swizzled source chunk

  u16* la0 = (u16*)(smem + wave * 16384);
  u16* la1 = (u16*)(smem + wave * 16384 + 4096);
  u16* lb0 = (u16*)(smem + wave * 16384 + 8192);
  u16* lb1 = (u16*)(smem + wave * 16384 + 12288);

  const u16* gA = xb + (size_t)(m0 + wr + r16) * 1024 + cswz * 8;
  const u16* gB = W  + (size_t)(n0 + wc + r16) * 1024 + cswz * 8;

  auto stage = [&](int k0, int b) {
    u16* la = b ? la1 : la0;
    u16* lb = b ? lb1 : lb0;
#pragma unroll
    for (int i = 0; i < 4; ++i) {
      gl_lds16(gA + k0 + (size_t)(i * 16) * 1024, la + i * 512);
      gl_lds16(gB + k0 + (size_t)(i * 16) * 1024, lb + i * 512);
    }
  };

  f32x4 acc[4][4] = {};
  stage(0, 0);

  for (int t = 0; t < 32; ++t) {
    const int cur = t & 1;
    if (t < 31) {
      stage((t + 1) * 32, cur ^ 1);
      asm volatile("s_waitcnt vmcnt(8)" ::: "memory");  // tile t's 8 loads done
    } else {
      asm volatile("s_waitcnt vmcnt(0)" ::: "memory");
    }
    __builtin_amdgcn_sched_barrier(0);
    const u16* Ac = cur ? la1 : la0;
    const u16* Bc = cur ? lb1 : lb0;
    short8 a[4], b[4];
#pragma unroll
    for (int i = 0; i < 4; ++i)
      a[i] = *(const short8*)(Ac + (i * 16 + fr) * 32 + ((fg ^ (fr & 3)) * 8));
#pragma unroll
    for (int i = 0; i < 4; ++i)
      b[i] = *(const short8*)(Bc + (i * 16 + fr) * 32 + ((fg ^ (fr & 3)) * 8));
    __builtin_amdgcn_s_setprio(1);
#pragma unroll
    for (int i = 0; i < 4; ++i)
#pragma unroll
      for (int j = 0; j < 4; ++j) acc[i][j] = mfma16(a[i], b[j], acc[i][j]);
    __builtin_amdgcn_s_setprio(0);
    // drain this iter's ds_reads before next iter overwrites the other buffer
    asm volatile("s_waitcnt lgkmcnt(0)" ::: "memory");
    __builtin_amdgcn_sched_barrier(0);
  }

  const float qsc = (z == 0) ? (0.125f * 1.44269504088896f) : 1.0f;
#pragma unroll
  for (int j = 0; j < 4; ++j) {
    const int col = n0 + wc + j * 16 + fr;
    const float bcol = bias[col];
    const int h = col >> 6, d = col & 63;
#pragma unroll
    for (int i = 0; i < 4; ++i) {
#pragma unroll
      for (int r = 0; r < 4; ++r) {
        const int m = m0 + wr + i * 16 + fg * 4 + r;
        const int bi = m >> 11, t = m & 2047;
        const u16 o = f2bf((acc[i][j][r] + bcol) * qsc);
        const size_t bse = (size_t)(bi * 16 + h) << 17;
        if (z == 0)      Qb[bse + (size_t)t * 64 + d] = o;
        else if (z == 1) Kb[bse + (size_t)t * 64 + d] = o;
        else             VTb[bse + (size_t)d * 2048 + t] = o;
      }
    }
  }
}

// ---------------- flash causal attention (coalesced LDS-staged K/V) ----------
// (byte-identical to R15/R20: best-measured 45.3-45.6 us)
__global__ __launch_bounds__(256, 2) void attn_kernel(
    const u16* __restrict__ Qb, const u16* __restrict__ Kb, const u16* __restrict__ VTb,
    u16* __restrict__ aOb) {
  __shared__ __align__(16) char smem[49152];  // 4 waves x (K0 4K | K1 4K | V 4K); epilogue Ow aliases
  __shared__ float Mll[4][2][64];             // l partials, 2 KB
  u16* Ow = (u16*)smem;
  const int id = blockIdx.x;
  const int xcd = id & 7, wbl = id >> 3;
  const int cu = wbl & 31, rr = wbl >> 5;
  const int g = cu >> 2;
  const int bh = xcd + ((cu & 3) << 3);
  const int j = (rr == 0) ? 31 - g : (rr == 1) ? 16 + g : (rr == 2) ? 15 - g : g;
  const int tid = threadIdx.x, lane = tid & 63, wave = tid >> 6;
  const int l31 = lane & 31, hi = lane >> 5;
  const size_t base = (size_t)bh << 17;
  const int bi = bh >> 4, h = bh & 15;
  const int q0 = j * 64;

  u16* kb0 = (u16*)(smem + wave * 12288);
  u16* kb1 = (u16*)(smem + wave * 12288 + 4096);
  u16* vb  = (u16*)(smem + wave * 12288 + 8192);

  short8 qf[2][4];
  {
    const u16* qp = Qb + base + (size_t)(q0 + l31) * 64 + hi * 8;
#pragma unroll
    for (int mi = 0; mi < 2; ++mi)
#pragma unroll
      for (int st = 0; st < 4; ++st)
        qf[mi][st] = *(const short8*)(qp + mi * 32 * 64 + st * 16);
  }

  f32x16 oacc[2][2] = {};
  float lrun[2] = {0.f, 0.f};

  auto stageK = [&](int t0, u16* kb) {
    const u16* kp = Kb + base + (size_t)(t0 + (lane >> 3)) * 64 +
                    (((lane & 7) ^ ((lane >> 3) & 7)) * 8);
#pragma unroll
    for (int i = 0; i < 4; ++i) gl_lds16(kp + (size_t)(8 * i) * 64, kb + i * 512);
  };
  auto stageV = [&](int t0) {
    const u16* vp = VTb + base + (size_t)(lane >> 2) * 2048 + t0 +
                    (((lane & 3) ^ ((lane >> 2) & 3)) * 8);
#pragma unroll
    for (int i = 0; i < 4; ++i) gl_lds16(vp + (size_t)(16 * i) * 2048, vb + i * 512);
  };

  const int tmax = 2 * j + 1;  // KV units of 32 tokens
  if (wave <= tmax) {
    int buf = 0;
    stageK(wave * 32, kb0);
    stageV(wave * 32);
    for (int tu = wave; tu <= tmax; tu += 4) {
      const int t0 = tu * 32;
      const bool more = (tu + 4 <= tmax);
      if (more) {
        stageK((tu + 4) * 32, buf ? kb0 : kb1);
        asm volatile("s_waitcnt vmcnt(4)" ::: "memory");
      } else {
        asm volatile("s_waitcnt vmcnt(0)" ::: "memory");
      }
      __builtin_amdgcn_sched_barrier(0);
      const char* kb = (const char*)(buf ? kb1 : kb0);

      short8 kf[4];
#pragma unroll
      for (int st = 0; st < 4; ++st)
        kf[st] = *(const short8*)(kb + l31 * 128 + (((st * 2 + hi) ^ (l31 & 7)) << 4));
      short8 vf[2][2];
#pragma unroll
      for (int nb = 0; nb < 2; ++nb)
#pragma unroll
        for (int ks = 0; ks < 2; ++ks)
          vf[nb][ks] = *(const short8*)((const char*)vb + (nb * 32 + l31) * 64 +
                                        (((ks * 2 + hi) ^ (l31 & 3)) << 4));

#pragma unroll
      for (int mi = 0; mi < 2; ++mi) {
        f32x16 s = {};
        __builtin_amdgcn_s_setprio(1);
        s = mfma32(kf[0], qf[mi][0], s);
        s = mfma32(kf[1], qf[mi][1], s);
        s = mfma32(kf[2], qf[mi][2], s);
        s = mfma32(kf[3], qf[mi][3], s);
        __builtin_amdgcn_s_setprio(0);

        if (t0 + 31 > q0 + mi * 32) {
          const int qv = q0 + mi * 32 + l31;
#pragma unroll
          for (int r = 0; r < 16; ++r) {
            const int tl = t0 + (r & 3) + ((r >> 2) << 3) + hi * 4;
            if (tl > qv) s[r] = -1e30f;
          }
        }

        float rs = 0.f;
#pragma unroll
        for (int r = 0; r < 16; ++r) {
          const float pv = exp2f(s[r]);
          s[r] = pv;
          rs += pv;
        }
        lrun[mi] += rs;

        uint32_t w0, w1, w2, w3, w4, w5, w6, w7;
        asm("v_cvt_pk_bf16_f32 %0, %1, %2" : "=v"(w0) : "v"(s[0]),  "v"(s[1]));
        asm("v_cvt_pk_bf16_f32 %0, %1, %2" : "=v"(w1) : "v"(s[2]),  "v"(s[3]));
        asm("v_cvt_pk_bf16_f32 %0, %1, %2" : "=v"(w2) : "v"(s[4]),  "v"(s[5]));
        asm("v_cvt_pk_bf16_f32 %0, %1, %2" : "=v"(w3) : "v"(s[6]),  "v"(s[7]));
        asm("v_cvt_pk_bf16_f32 %0, %1, %2" : "=v"(w4) : "v"(s[8]),  "v"(s[9]));
        asm("v_cvt_pk_bf16_f32 %0, %1, %2" : "=v"(w5) : "v"(s[10]), "v"(s[11]));
        asm("v_cvt_pk_bf16_f32 %0, %1, %2" : "=v"(w6) : "v"(s[12]), "v"(s[13]));
        asm("v_cvt_pk_bf16_f32 %0, %1, %2" : "=v"(w7) : "v"(s[14]), "v"(s[15]));
        asm("v_permlane32_swap_b32 %0, %1" : "+v"(w0), "+v"(w2));
        asm("v_permlane32_swap_b32 %0, %1" : "+v"(w1), "+v"(w3));
        asm("v_permlane32_swap_b32 %0, %1" : "+v"(w4), "+v"(w6));
        asm("v_permlane32_swap_b32 %0, %1" : "+v"(w5), "+v"(w7));
        short8 pa0, pa1;
        {
          uint32_t* p0 = (uint32_t*)&pa0;
          p0[0] = w0; p0[1] = w1; p0[2] = w2; p0[3] = w3;
          uint32_t* p1 = (uint32_t*)&pa1;
          p1[0] = w4; p1[1] = w5; p1[2] = w6; p1[3] = w7;
        }

        __builtin_amdgcn_s_setprio(1);
        oacc[mi][0] = mfma32(pa0, vf[0][0], oacc[mi][0]);
        oacc[mi][0] = mfma32(pa1, vf[0][1], oacc[mi][0]);
        oacc[mi][1] = mfma32(pa0, vf[1][0], oacc[mi][1]);
        oacc[mi][1] = mfma32(pa1, vf[1][1], oacc[mi][1]);
        __builtin_amdgcn_s_setprio(0);
      }

      if (more) {
        asm volatile("s_waitcnt lgkmcnt(0)" ::: "memory");
        __builtin_amdgcn_sched_barrier(0);
        stageV((tu + 4) * 32);
      }
      buf ^= 1;
    }
  }

  __syncthreads();  // staging LDS dead; Ow takes over the aliased space
#pragma unroll
  for (int mi = 0; mi < 2; ++mi) Mll[wave][hi][mi * 32 + l31] = lrun[mi];
#pragma unroll
  for (int mi = 0; mi < 2; ++mi)
#pragma unroll
    for (int nb = 0; nb < 2; ++nb)
#pragma unroll
      for (int r = 0; r < 16; ++r) {
        const int q = mi * 32 + (r & 3) + ((r >> 2) << 3) + hi * 4;
        Ow[(wave * 64 + q) * 72 + nb * 32 + l31] = f2bf(oacc[mi][nb][r]);
      }
  __syncthreads();

  const int rq = tid >> 2, c0 = (tid & 3) * 16;
  float lt = 0.f;
#pragma unroll
  for (int w = 0; w < 4; ++w)
#pragma unroll
    for (int gg = 0; gg < 2; ++gg) lt += Mll[w][gg][rq];
  const float inv = __builtin_amdgcn_rcpf(lt);
  float o[16] = {};
#pragma unroll
  for (int w = 0; w < 4; ++w) {
    const u16* orow = &Ow[(w * 64 + rq) * 72 + c0];
    short8 a = *(const short8*)orow;
    short8 b = *(const short8*)(orow + 8);
#pragma unroll
    for (int i = 0; i < 8; ++i) {
      o[i]     += bf2f((u16)a[i]);
      o[8 + i] += bf2f((u16)b[i]);
    }
  }
  short8 r0, r1;
#pragma unroll
  for (int i = 0; i < 8; ++i) {
    r0[i] = (short)f2bf(o[i] * inv);
    r1[i] = (short)f2bf(o[8 + i] * inv);
  }
  u16* op = aOb + ((size_t)bi * 2048 + q0 + rq) * 1024 + h * 64 + c0;
  *(short8*)op = r0;
  *(short8*)(op + 8) = r1;
}

// ---------------- output projection GEMM (wave-private, barrier-free) --------
__global__ __launch_bounds__(256) void out_gemm(
    const u16* __restrict__ Ab, const u16* __restrict__ Wb, const float* __restrict__ bo,
    float* __restrict__ out) {
  __shared__ __align__(16) char smem[65536];
  const int id = blockIdx.x;
  const int s = id >> 3;
  const int m0 = ((id & 7) + ((s & 3) << 3)) * 128;
  const int n0 = (s >> 2) * 128;
  const int tid = threadIdx.x, lane = tid & 63, wave = tid >> 6;
  const int wr = (wave >> 1) * 64, wc = (wave & 1) * 64;
  const int fr = lane & 15, fg = lane >> 4;
  const int r16 = lane >> 2;
  const int cswz = (lane & 3) ^ (r16 & 3);

  u16* la0 = (u16*)(smem + wave * 16384);
  u16* la1 = (u16*)(smem + wave * 16384 + 4096);
  u16* lb0 = (u16*)(smem + wave * 16384 + 8192);
  u16* lb1 = (u16*)(smem + wave * 16384 + 12288);

  const u16* gA = Ab + (size_t)(m0 + wr + r16) * 1024 + cswz * 8;
  const u16* gB = Wb + (size_t)(n0 + wc + r16) * 1024 + cswz * 8;

  auto stage = [&](int k0, int b) {
    u16* la = b ? la1 : la0;
    u16* lb = b ? lb1 : lb0;
#pragma unroll
    for (int i = 0; i < 4; ++i) {
      gl_lds16(gA + k0 + (size_t)(i * 16) * 1024, la + i * 512);
      gl_lds16(gB + k0 + (size_t)(i * 16) * 1024, lb + i * 512);
    }
  };

  f32x4 acc[4][4] = {};
  stage(0, 0);

  for (int t = 0; t < 32; ++t) {
    const int cur = t & 1;
    if (t < 31) {
      stage((t + 1) * 32, cur ^ 1);
      asm volatile("s_waitcnt vmcnt(8)" ::: "memory");
    } else {
      asm volatile("s_waitcnt vmcnt(0)" ::: "memory");
    }
    __builtin_amdgcn_sched_barrier(0);
    const u16* Ac = cur ? la1 : la0;
    const u16* Bc = cur ? lb1 : lb0;
    short8 a[4], b[4];
#pragma unroll
    for (int i = 0; i < 4; ++i)
      a[i] = *(const short8*)(Ac + (i * 16 + fr) * 32 + ((fg ^ (fr & 3)) * 8));
#pragma unroll
    for (int i = 0; i < 4; ++i)
      b[i] = *(const short8*)(Bc + (i * 16 + fr) * 32 + ((fg ^ (fr & 3)) * 8));
    __builtin_amdgcn_s_setprio(1);
#pragma unroll
    for (int i = 0; i < 4; ++i)
#pragma unroll
      for (int j = 0; j < 4; ++j) acc[i][j] = mfma16(a[i], b[j], acc[i][j]);
    __builtin_amdgcn_s_setprio(0);
    asm volatile("s_waitcnt lgkmcnt(0)" ::: "memory");
    __builtin_amdgcn_sched_barrier(0);
  }

#pragma unroll
  for (int j = 0; j < 4; ++j) {
    const int col = n0 + wc + j * 16 + fr;
    const float bcol = bo[col];
#pragma unroll
    for (int i = 0; i < 4; ++i)
#pragma unroll
      for (int r = 0; r < 4; ++r) {
        const int m = m0 + wr + i * 16 + fg * 4 + r;
        out[(size_t)m * 1024 + col] = acc[i][j][r] + bcol;
      }
  }
}

extern "C" void kernel_launch(void* const* d_in, const int* in_sizes, int n_in,
                              void* d_out, int out_size, void* d_ws, size_t ws_size,
                              hipStream_t stream) {
  (void)in_sizes; (void)n_in; (void)out_size; (void)ws_size;
  const float* x  = (const float*)d_in[0];
  const float* Wq = (const float*)d_in[1];
  const float* bq = (const float*)d_in[2];
  const float* Wk = (const float*)d_in[3];
  const float* bk = (const float*)d_in[4];
  const float* Wv = (const float*)d_in[5];
  const float* bv = (const float*)d_in[6];
  const float* Wo = (const float*)d_in[7];
  const float* bo = (const float*)d_in[8];
  float* out = (float*)d_out;
  char* ws = (char*)d_ws;

  const size_t MB = 1024 * 1024;
  u16* xb  = (u16*)(ws);
  u16* wqb = (u16*)(ws + 8 * MB);
  u16* wkb = (u16*)(ws + 10 * MB);
  u16* wvb = (u16*)(ws + 12 * MB);
  u16* wob = (u16*)(ws + 14 * MB);
  u16* Qb  = (u16*)(ws + 16 * MB);
  u16* Kb  = (u16*)(ws + 24 * MB);
  u16* VTb = (u16*)(ws + 32 * MB);
  u16* aOb = (u16*)(ws + 40 * MB);

  cast_all<<<8192, 256, 0, stream>>>(x, Wq, Wk, Wv, Wo, xb, wqb, wkb, wvb, wob);
  qkv_gemm<<<768, 256, 0, stream>>>(xb, wqb, wkb, wvb, bq, bk, bv, Qb, Kb, VTb);
  attn_kernel<<<1024, 256, 0, stream>>>(Qb, Kb, VTb, aOb);
  out_gemm<<<256, 256, 0, stream>>>(aOb, wob, bo, out);
}

// Round 22
// 112.706 us; speedup vs baseline: 1.0544x; 1.0544x over previous
//
#include <hip/hip_runtime.h>
#include <stdint.h>

typedef unsigned short u16;
typedef __attribute__((ext_vector_type(8))) short short8;
typedef __attribute__((ext_vector_type(8))) unsigned short ushort8;
typedef __attribute__((ext_vector_type(4))) float f32x4;
typedef __attribute__((ext_vector_type(16))) float f32x16;

__device__ __forceinline__ u16 f2bf(float f) {
  union { float f; unsigned int u; } c; c.f = f;
  return (u16)((c.u + 0x7FFFu + ((c.u >> 16) & 1u)) >> 16);
}

__device__ __forceinline__ float bf2f(u16 v) {
  union { unsigned int u; float f; } c; c.u = ((unsigned int)v) << 16;
  return c.f;
}

__device__ __forceinline__ f32x4 mfma16(short8 a, short8 b, f32x4 c) {
  return __builtin_amdgcn_mfma_f32_16x16x32_bf16(a, b, c, 0, 0, 0);
}

__device__ __forceinline__ f32x16 mfma32(short8 a, short8 b, f32x16 c) {
  return __builtin_amdgcn_mfma_f32_32x32x16_bf16(a, b, c, 0, 0, 0);
}

__device__ __forceinline__ void gl_lds16(const u16* g, u16* l) {
  __builtin_amdgcn_global_load_lds((const __attribute__((address_space(1))) void*)g,
                                   (__attribute__((address_space(3))) void*)l, 16, 0, 0);
}

// ---------------- fused cast f32 -> bf16 (2x float4 -> ushort8 per thread) ---
// 16B/lane stores (was 8B): half the store instructions, full write segments.
__global__ __launch_bounds__(256) void cast_all(
    const float* __restrict__ x, const float* __restrict__ wq, const float* __restrict__ wk,
    const float* __restrict__ wv, const float* __restrict__ wo,
    u16* __restrict__ xb, u16* __restrict__ wqb, u16* __restrict__ wkb,
    u16* __restrict__ wvb, u16* __restrict__ wob) {
  int b = blockIdx.x;
  const float* src; u16* dst; int i;
  if (b < 2048)      { src = x;  dst = xb;  i = b * 256 + threadIdx.x; }
  else if (b < 2560) { src = wq; dst = wqb; i = (b - 2048) * 256 + threadIdx.x; }
  else if (b < 3072) { src = wk; dst = wkb; i = (b - 2560) * 256 + threadIdx.x; }
  else if (b < 3584) { src = wv; dst = wvb; i = (b - 3072) * 256 + threadIdx.x; }
  else               { src = wo; dst = wob; i = (b - 3584) * 256 + threadIdx.x; }
  float4 v0 = ((const float4*)src)[2 * i];
  float4 v1 = ((const float4*)src)[2 * i + 1];
  ushort8 o;
  o[0] = f2bf(v0.x); o[1] = f2bf(v0.y); o[2] = f2bf(v0.z); o[3] = f2bf(v0.w);
  o[4] = f2bf(v1.x); o[5] = f2bf(v1.y); o[6] = f2bf(v1.z); o[7] = f2bf(v1.w);
  ((ushort8*)dst)[i] = o;
}

// ---------------- fused QKV projection GEMM (R20 exact: best-measured) ------
__global__ __launch_bounds__(256) void qkv_gemm(
    const u16* __restrict__ xb, const u16* __restrict__ wqb, const u16* __restrict__ wkb,
    const u16* __restrict__ wvb, const float* __restrict__ bq, const float* __restrict__ bk,
    const float* __restrict__ bv, u16* __restrict__ Qb, u16* __restrict__ Kb,
    u16* __restrict__ VTb) {
  __shared__ __align__(16) u16 As[128 * 32];
  __shared__ __align__(16) u16 Bs[128 * 32];
  const int id = blockIdx.x;
  const int z = id >> 8;
  const int u = id & 255;
  const int mblk = (u & 7) + (((u >> 3) & 3) << 3);
  const int nblk = u >> 5;
  const u16* __restrict__ W = (z == 0) ? wqb : (z == 1) ? wkb : wvb;
  const float* __restrict__ bias = (z == 0) ? bq : (z == 1) ? bk : bv;
  const int m0 = mblk * 128, n0 = nblk * 128;
  const int tid = threadIdx.x, lane = tid & 63, wave = tid >> 6;
  const int wr = (wave >> 1) * 64, wc = (wave & 1) * 64;
  const int fr = lane & 15, fg = lane >> 4;
  const int lrow = lane >> 2, lcol = (lane & 3) * 8;

  const u16* ga = xb + (size_t)(m0 + wave * 16 + lrow) * 1024 + lcol;
  const u16* gb = W  + (size_t)(n0 + wave * 16 + lrow) * 1024 + lcol;
  u16* la = As + wave * 512;
  u16* lb = Bs + wave * 512;

  f32x4 acc[4][4] = {};

  for (int k0 = 0; k0 < 1024; k0 += 32) {
    gl_lds16(ga + k0, la);
    gl_lds16(ga + 64 * 1024 + k0, la + 2048);
    gl_lds16(gb + k0, lb);
    gl_lds16(gb + 64 * 1024 + k0, lb + 2048);
    __syncthreads();
    short8 a[4], b[4];
#pragma unroll
    for (int i = 0; i < 4; ++i) a[i] = *(const short8*)(As + (wr + i * 16 + fr) * 32 + fg * 8);
#pragma unroll
    for (int i = 0; i < 4; ++i) b[i] = *(const short8*)(Bs + (wc + i * 16 + fr) * 32 + fg * 8);
#pragma unroll
    for (int i = 0; i < 4; ++i)
#pragma unroll
      for (int j = 0; j < 4; ++j) acc[i][j] = mfma16(a[i], b[j], acc[i][j]);
    __syncthreads();
  }

  const float qsc = (z == 0) ? (0.125f * 1.44269504088896f) : 1.0f;
#pragma unroll
  for (int j = 0; j < 4; ++j) {
    const int col = n0 + wc + j * 16 + fr;
    const float bcol = bias[col];
    const int h = col >> 6, d = col & 63;
#pragma unroll
    for (int i = 0; i < 4; ++i) {
#pragma unroll
      for (int r = 0; r < 4; ++r) {
        const int m = m0 + wr + i * 16 + fg * 4 + r;
        const int bi = m >> 11, t = m & 2047;
        const u16 o = f2bf((acc[i][j][r] + bcol) * qsc);
        const size_t bse = (size_t)(bi * 16 + h) << 17;
        if (z == 0)      Qb[bse + (size_t)t * 64 + d] = o;
        else if (z == 1) Kb[bse + (size_t)t * 64 + d] = o;
        else             VTb[bse + (size_t)d * 2048 + t] = o;
      }
    }
  }
}

// ---------------- flash causal attention (R15/R20 exact: best-measured) ------
__global__ __launch_bounds__(256, 2) void attn_kernel(
    const u16* __restrict__ Qb, const u16* __restrict__ Kb, const u16* __restrict__ VTb,
    u16* __restrict__ aOb) {
  __shared__ __align__(16) char smem[49152];  // 4 waves x (K0 4K | K1 4K | V 4K); epilogue Ow aliases
  __shared__ float Mll[4][2][64];             // l partials, 2 KB
  u16* Ow = (u16*)smem;
  const int id = blockIdx.x;
  const int xcd = id & 7, wbl = id >> 3;
  const int cu = wbl & 31, rr = wbl >> 5;
  const int g = cu >> 2;
  const int bh = xcd + ((cu & 3) << 3);
  const int j = (rr == 0) ? 31 - g : (rr == 1) ? 16 + g : (rr == 2) ? 15 - g : g;
  const int tid = threadIdx.x, lane = tid & 63, wave = tid >> 6;
  const int l31 = lane & 31, hi = lane >> 5;
  const size_t base = (size_t)bh << 17;
  const int bi = bh >> 4, h = bh & 15;
  const int q0 = j * 64;

  u16* kb0 = (u16*)(smem + wave * 12288);
  u16* kb1 = (u16*)(smem + wave * 12288 + 4096);
  u16* vb  = (u16*)(smem + wave * 12288 + 8192);

  short8 qf[2][4];
  {
    const u16* qp = Qb + base + (size_t)(q0 + l31) * 64 + hi * 8;
#pragma unroll
    for (int mi = 0; mi < 2; ++mi)
#pragma unroll
      for (int st = 0; st < 4; ++st)
        qf[mi][st] = *(const short8*)(qp + mi * 32 * 64 + st * 16);
  }

  f32x16 oacc[2][2] = {};
  float lrun[2] = {0.f, 0.f};

  auto stageK = [&](int t0, u16* kb) {
    const u16* kp = Kb + base + (size_t)(t0 + (lane >> 3)) * 64 +
                    (((lane & 7) ^ ((lane >> 3) & 7)) * 8);
#pragma unroll
    for (int i = 0; i < 4; ++i) gl_lds16(kp + (size_t)(8 * i) * 64, kb + i * 512);
  };
  auto stageV = [&](int t0) {
    const u16* vp = VTb + base + (size_t)(lane >> 2) * 2048 + t0 +
                    (((lane & 3) ^ ((lane >> 2) & 3)) * 8);
#pragma unroll
    for (int i = 0; i < 4; ++i) gl_lds16(vp + (size_t)(16 * i) * 2048, vb + i * 512);
  };

  const int tmax = 2 * j + 1;  // KV units of 32 tokens
  if (wave <= tmax) {
    int buf = 0;
    stageK(wave * 32, kb0);
    stageV(wave * 32);
    for (int tu = wave; tu <= tmax; tu += 4) {
      const int t0 = tu * 32;
      const bool more = (tu + 4 <= tmax);
      if (more) {
        stageK((tu + 4) * 32, buf ? kb0 : kb1);
        asm volatile("s_waitcnt vmcnt(4)" ::: "memory");
      } else {
        asm volatile("s_waitcnt vmcnt(0)" ::: "memory");
      }
      __builtin_amdgcn_sched_barrier(0);
      const char* kb = (const char*)(buf ? kb1 : kb0);

      short8 kf[4];
#pragma unroll
      for (int st = 0; st < 4; ++st)
        kf[st] = *(const short8*)(kb + l31 * 128 + (((st * 2 + hi) ^ (l31 & 7)) << 4));
      short8 vf[2][2];
#pragma unroll
      for (int nb = 0; nb < 2; ++nb)
#pragma unroll
        for (int ks = 0; ks < 2; ++ks)
          vf[nb][ks] = *(const short8*)((const char*)vb + (nb * 32 + l31) * 64 +
                                        (((ks * 2 + hi) ^ (l31 & 3)) << 4));

#pragma unroll
      for (int mi = 0; mi < 2; ++mi) {
        f32x16 s = {};
        __builtin_amdgcn_s_setprio(1);
        s = mfma32(kf[0], qf[mi][0], s);
        s = mfma32(kf[1], qf[mi][1], s);
        s = mfma32(kf[2], qf[mi][2], s);
        s = mfma32(kf[3], qf[mi][3], s);
        __builtin_amdgcn_s_setprio(0);

        if (t0 + 31 > q0 + mi * 32) {
          const int qv = q0 + mi * 32 + l31;
#pragma unroll
          for (int r = 0; r < 16; ++r) {
            const int tl = t0 + (r & 3) + ((r >> 2) << 3) + hi * 4;
            if (tl > qv) s[r] = -1e30f;
          }
        }

        float rs = 0.f;
#pragma unroll
        for (int r = 0; r < 16; ++r) {
          const float pv = exp2f(s[r]);
          s[r] = pv;
          rs += pv;
        }
        lrun[mi] += rs;

        uint32_t w0, w1, w2, w3, w4, w5, w6, w7;
        asm("v_cvt_pk_bf16_f32 %0, %1, %2" : "=v"(w0) : "v"(s[0]),  "v"(s[1]));
        asm("v_cvt_pk_bf16_f32 %0, %1, %2" : "=v"(w1) : "v"(s[2]),  "v"(s[3]));
        asm("v_cvt_pk_bf16_f32 %0, %1, %2" : "=v"(w2) : "v"(s[4]),  "v"(s[5]));
        asm("v_cvt_pk_bf16_f32 %0, %1, %2" : "=v"(w3) : "v"(s[6]),  "v"(s[7]));
        asm("v_cvt_pk_bf16_f32 %0, %1, %2" : "=v"(w4) : "v"(s[8]),  "v"(s[9]));
        asm("v_cvt_pk_bf16_f32 %0, %1, %2" : "=v"(w5) : "v"(s[10]), "v"(s[11]));
        asm("v_cvt_pk_bf16_f32 %0, %1, %2" : "=v"(w6) : "v"(s[12]), "v"(s[13]));
        asm("v_cvt_pk_bf16_f32 %0, %1, %2" : "=v"(w7) : "v"(s[14]), "v"(s[15]));
        asm("v_permlane32_swap_b32 %0, %1" : "+v"(w0), "+v"(w2));
        asm("v_permlane32_swap_b32 %0, %1" : "+v"(w1), "+v"(w3));
        asm("v_permlane32_swap_b32 %0, %1" : "+v"(w4), "+v"(w6));
        asm("v_permlane32_swap_b32 %0, %1" : "+v"(w5), "+v"(w7));
        short8 pa0, pa1;
        {
          uint32_t* p0 = (uint32_t*)&pa0;
          p0[0] = w0; p0[1] = w1; p0[2] = w2; p0[3] = w3;
          uint32_t* p1 = (uint32_t*)&pa1;
          p1[0] = w4; p1[1] = w5; p1[2] = w6; p1[3] = w7;
        }

        __builtin_amdgcn_s_setprio(1);
        oacc[mi][0] = mfma32(pa0, vf[0][0], oacc[mi][0]);
        oacc[mi][0] = mfma32(pa1, vf[0][1], oacc[mi][0]);
        oacc[mi][1] = mfma32(pa0, vf[1][0], oacc[mi][1]);
        oacc[mi][1] = mfma32(pa1, vf[1][1], oacc[mi][1]);
        __builtin_amdgcn_s_setprio(0);
      }

      if (more) {
        asm volatile("s_waitcnt lgkmcnt(0)" ::: "memory");
        __builtin_amdgcn_sched_barrier(0);
        stageV((tu + 4) * 32);
      }
      buf ^= 1;
    }
  }

  __syncthreads();  // staging LDS dead; Ow takes over the aliased space
#pragma unroll
  for (int mi = 0; mi < 2; ++mi) Mll[wave][hi][mi * 32 + l31] = lrun[mi];
#pragma unroll
  for (int mi = 0; mi < 2; ++mi)
#pragma unroll
    for (int nb = 0; nb < 2; ++nb)
#pragma unroll
      for (int r = 0; r < 16; ++r) {
        const int q = mi * 32 + (r & 3) + ((r >> 2) << 3) + hi * 4;
        Ow[(wave * 64 + q) * 72 + nb * 32 + l31] = f2bf(oacc[mi][nb][r]);
      }
  __syncthreads();

  const int rq = tid >> 2, c0 = (tid & 3) * 16;
  float lt = 0.f;
#pragma unroll
  for (int w = 0; w < 4; ++w)
#pragma unroll
    for (int gg = 0; gg < 2; ++gg) lt += Mll[w][gg][rq];
  const float inv = __builtin_amdgcn_rcpf(lt);
  float o[16] = {};
#pragma unroll
  for (int w = 0; w < 4; ++w) {
    const u16* orow = &Ow[(w * 64 + rq) * 72 + c0];
    short8 a = *(const short8*)orow;
    short8 b = *(const short8*)(orow + 8);
#pragma unroll
    for (int i = 0; i < 8; ++i) {
      o[i]     += bf2f((u16)a[i]);
      o[8 + i] += bf2f((u16)b[i]);
    }
  }
  short8 r0, r1;
#pragma unroll
  for (int i = 0; i < 8; ++i) {
    r0[i] = (short)f2bf(o[i] * inv);
    r1[i] = (short)f2bf(o[8 + i] * inv);
  }
  u16* op = aOb + ((size_t)bi * 2048 + q0 + rq) * 1024 + h * 64 + c0;
  *(short8*)op = r0;
  *(short8*)(op + 8) = r1;
}

// ---------------- output projection GEMM (R20 exact) -------------------------
__global__ __launch_bounds__(256) void out_gemm(
    const u16* __restrict__ Ab, const u16* __restrict__ Wb, const float* __restrict__ bo,
    float* __restrict__ out) {
  __shared__ __align__(16) u16 As[128 * 32];
  __shared__ __align__(16) u16 Bs[128 * 32];
  const int id = blockIdx.x;
  const int s = id >> 3;
  const int m0 = ((id & 7) + ((s & 3) << 3)) * 128;
  const int n0 = (s >> 2) * 128;
  const int tid = threadIdx.x, lane = tid & 63, wave = tid >> 6;
  const int wr = (wave >> 1) * 64, wc = (wave & 1) * 64;
  const int fr = lane & 15, fg = lane >> 4;
  const int lrow = lane >> 2, lcol = (lane & 3) * 8;

  const u16* ga = Ab + (size_t)(m0 + wave * 16 + lrow) * 1024 + lcol;
  const u16* gb = Wb + (size_t)(n0 + wave * 16 + lrow) * 1024 + lcol;
  u16* la = As + wave * 512;
  u16* lb = Bs + wave * 512;

  f32x4 acc[4][4] = {};

  for (int k0 = 0; k0 < 1024; k0 += 32) {
    gl_lds16(ga + k0, la);
    gl_lds16(ga + 64 * 1024 + k0, la + 2048);
    gl_lds16(gb + k0, lb);
    gl_lds16(gb + 64 * 1024 + k0, lb + 2048);
    __syncthreads();
    short8 a[4], b[4];
#pragma unroll
    for (int i = 0; i < 4; ++i) a[i] = *(const short8*)(As + (wr + i * 16 + fr) * 32 + fg * 8);
#pragma unroll
    for (int i = 0; i < 4; ++i) b[i] = *(const short8*)(Bs + (wc + i * 16 + fr) * 32 + fg * 8);
#pragma unroll
    for (int i = 0; i < 4; ++i)
#pragma unroll
      for (int j = 0; j < 4; ++j) acc[i][j] = mfma16(a[i], b[j], acc[i][j]);
    __syncthreads();
  }

#pragma unroll
  for (int j = 0; j < 4; ++j) {
    const int col = n0 + wc + j * 16 + fr;
    const float bcol = bo[col];
#pragma unroll
    for (int i = 0; i < 4; ++i)
#pragma unroll
      for (int r = 0; r < 4; ++r) {
        const int m = m0 + wr + i * 16 + fg * 4 + r;
        out[(size_t)m * 1024 + col] = acc[i][j][r] + bcol;
      }
  }
}

extern "C" void kernel_launch(void* const* d_in, const int* in_sizes, int n_in,
                              void* d_out, int out_size, void* d_ws, size_t ws_size,
                              hipStream_t stream) {
  (void)in_sizes; (void)n_in; (void)out_size; (void)ws_size;
  const float* x  = (const float*)d_in[0];
  const float* Wq = (const float*)d_in[1];
  const float* bq = (const float*)d_in[2];
  const float* Wk = (const float*)d_in[3];
  const float* bk = (const float*)d_in[4];
  const float* Wv = (const float*)d_in[5];
  const float* bv = (const float*)d_in[6];
  const float* Wo = (const float*)d_in[7];
  const float* bo = (const float*)d_in[8];
  float* out = (float*)d_out;
  char* ws = (char*)d_ws;

  const size_t MB = 1024 * 1024;
  u16* xb  = (u16*)(ws);
  u16* wqb = (u16*)(ws + 8 * MB);
  u16* wkb = (u16*)(ws + 10 * MB);
  u16* wvb = (u16*)(ws + 12 * MB);
  u16* wob = (u16*)(ws + 14 * MB);
  u16* Qb  = (u16*)(ws + 16 * MB);
  u16* Kb  = (u16*)(ws + 24 * MB);
  u16* VTb = (u16*)(ws + 32 * MB);
  u16* aOb = (u16*)(ws + 40 * MB);

  cast_all<<<4096, 256, 0, stream>>>(x, Wq, Wk, Wv, Wo, xb, wqb, wkb, wvb, wob);
  qkv_gemm<<<768, 256, 0, stream>>>(xb, wqb, wkb, wvb, bq, bk, bv, Qb, Kb, VTb);
  attn_kernel<<<1024, 256, 0, stream>>>(Qb, Kb, VTb, aOb);
  out_gemm<<<256, 256, 0, stream>>>(aOb, wob, bo, out);
}